// Round 3
// baseline (85.558 us; speedup 1.0000x reference)
//
#include <hip/hip_runtime.h>
#include <math.h>

#define BB 8
#define HH 16
#define NN 1024
#define TB 256

// ws layout (floats): ws[bh*4 + q] = sum over own-quarter q's 256 points of
// full min_j d2(reflected_i, sp_j). 128*4 = 512 floats. Written once, plain
// stores, no atomics, no init required.

// ---------------------------------------------------------------------------
// chamfer: ONLY pass A is computed (reflection-isometry identity makes both
// chamfer terms equal). Block (bh, q): own = reflected points [q*256,+256)
// (1/thread, pre-scaled by -2), scan = ALL 1024 points so min_j completes
// in-block and the i-sum collapses to ONE float per block.
//
// ROUND-3 CHANGE: the scan coordinate stream is moved OFF the LDS pipe.
// Rounds 0-2 were LDS-issue-bound: 512-1024 broadcast ds_read_b128 per wave
// at ~9-12 cyc each on the per-CU LDS pipe (~30-40 us/CU) dwarfed the ~6.4 us
// of FMA work. Scan xyz is wave-UNIFORM (index j is a loop counter), so it
// is read through a uniform pointer -> compiler emits s_load_dwordx16/x8
// into SGPRs on the SMEM pipe (separate from VALU and LDS); each FMA reads
// one SGPR operand (legal: <=1 SGPR per VALU instr). Only sq_j stays in LDS
// (1 broadcast ds_read_b128 per 4 points = ~3 cyc/pair, under the 7 cyc/pair
// VALU cost). All arithmetic expression trees are bit-identical to round 2.
// ---------------------------------------------------------------------------
__global__ __launch_bounds__(TB) void chamfer_kernel(
    const float* __restrict__ y_pred,
    const float* __restrict__ sp,
    float* __restrict__ ws)
{
    __shared__ __align__(16) float sqs[NN];   // 4 KB: squared norms only
    __shared__ float wsum[4];

    const int blk = blockIdx.x;          // 512 blocks
    const int bh  = blk >> 2;
    const int q   = blk & 3;
    const int b   = bh >> 4;             // HH = 16
    const int tid = threadIdx.x;

    float pnx = y_pred[bh * 4 + 0];
    float pny = y_pred[bh * 4 + 1];
    float pnz = y_pred[bh * 4 + 2];
    float pd  = y_pred[bh * 4 + 3];
    float inv = 1.0f / sqrtf(pnx * pnx + pny * pny + pnz * pnz);
    pnx *= inv; pny *= inv; pnz *= inv;

    const float* __restrict__ spb = sp + (size_t)b * NN * 3;

    // stage squared norms (same expression as round 2: x*x + y*y + z*z)
    for (int k = tid; k < NN; k += TB) {
        float x = spb[k * 3 + 0], y = spb[k * 3 + 1], z = spb[k * 3 + 2];
        sqs[k] = x * x + y * y + z * z;
    }

    // own point: reflected, pre-scaled by -2 (identical to round 2)
    float mx, my, mz, osq;
    {
        int i = q * TB + tid;
        float x = spb[i * 3 + 0], y = spb[i * 3 + 1], z = spb[i * 3 + 2];
        float proj = x * pnx + y * pny + z * pnz + pd;
        x -= 2.0f * proj * pnx;
        y -= 2.0f * proj * pny;
        z -= 2.0f * proj * pnz;
        osq = x * x + y * y + z * z;
        mx = -2.0f * x; my = -2.0f * y; mz = -2.0f * z;
    }
    __syncthreads();

    float m0 = 3.4e38f, m1 = 3.4e38f;
    const float4* __restrict__ sq4 = (const float4*)sqs;

#define DIST(X, Y, Z, W) fmaf(mx, X, fmaf(my, Y, fmaf(mz, Z, W)))
    for (int j = 0; j < NN; j += 8) {
        // sq for 8 points: two broadcast ds_read_b128 (only LDS traffic)
        float4 s0 = sq4[(j >> 2) + 0];
        float4 s1 = sq4[(j >> 2) + 1];
        // xyz for 8 points: 24 contiguous dwords at a wave-uniform address
        // -> s_load_dwordx16 + s_load_dwordx8 (SMEM pipe, not LDS/VMEM)
        const float* __restrict__ pj = spb + j * 3;
        float x0 = pj[ 0], y0 = pj[ 1], z0 = pj[ 2];
        float x1 = pj[ 3], y1 = pj[ 4], z1 = pj[ 5];
        float x2 = pj[ 6], y2 = pj[ 7], z2 = pj[ 8];
        float x3 = pj[ 9], y3 = pj[10], z3 = pj[11];
        float x4 = pj[12], y4 = pj[13], z4 = pj[14];
        float x5 = pj[15], y5 = pj[16], z5 = pj[17];
        float x6 = pj[18], y6 = pj[19], z6 = pj[20];
        float x7 = pj[21], y7 = pj[22], z7 = pj[23];
        float d0 = DIST(x0, y0, z0, s0.x);
        float d1 = DIST(x1, y1, z1, s0.y);
        float d2 = DIST(x2, y2, z2, s0.z);
        float d3 = DIST(x3, y3, z3, s0.w);
        float d4 = DIST(x4, y4, z4, s1.x);
        float d5 = DIST(x5, y5, z5, s1.y);
        float d6 = DIST(x6, y6, z6, s1.z);
        float d7 = DIST(x7, y7, z7, s1.w);
        // same accumulator pairing as round 2 (bit-identical, min3-friendly)
        m0 = fminf(fminf(m0, d0), d1);
        m1 = fminf(fminf(m1, d2), d3);
        m0 = fminf(fminf(m0, d4), d5);
        m1 = fminf(fminf(m1, d6), d7);
    }
#undef DIST

    float dmin = osq + fminf(m0, m1);      // complete min_j d2 for own i

    // in-block sum over 256 own points (deterministic, same as round 2)
    float s = dmin;
    for (int off = 32; off; off >>= 1) s += __shfl_down(s, off, 64);
    if ((tid & 63) == 0) wsum[tid >> 6] = s;
    __syncthreads();
    if (tid == 0)
        ws[bh * 4 + q] = (wsum[0] + wsum[1]) + (wsum[2] + wsum[3]);
}

// ---------------------------------------------------------------------------
// finalize (per batch, 256 threads): centroid; sde[h] = 2/N * (4 block sums
// in fixed order); conf; angle-NMS; stable rank; write. Verbatim round 2.
// ---------------------------------------------------------------------------
__global__ __launch_bounds__(TB) void finalize_kernel(
    const float* __restrict__ ws,
    const float* __restrict__ y_pred,
    const float* __restrict__ sp,
    float* __restrict__ out)
{
    const int b   = blockIdx.x;
    const int tid = threadIdx.x;

    __shared__ float sde_s[HH], nx_s[HH], ny_s[HH], nz_s[HH], d_s[HH], conf_s[HH];
    __shared__ float cmacc[3];
    __shared__ int keep_s[HH];

    if (tid < 3) cmacc[tid] = 0.0f;
    __syncthreads();

    // centroid: 1024 samples over 256 threads
    const float* spb = sp + (size_t)b * NN * 3;
    float sx = 0.0f, sy = 0.0f, sz = 0.0f;
    for (int p = tid; p < NN; p += TB) {
        sx += spb[p * 3 + 0];
        sy += spb[p * 3 + 1];
        sz += spb[p * 3 + 2];
    }
    for (int off = 32; off; off >>= 1) {
        sx += __shfl_down(sx, off, 64);
        sy += __shfl_down(sy, off, 64);
        sz += __shfl_down(sz, off, 64);
    }
    if ((tid & 63) == 0) {
        atomicAdd(&cmacc[0], sx);
        atomicAdd(&cmacc[1], sy);
        atomicAdd(&cmacc[2], sz);
    }
    __syncthreads();

    const float cmx = cmacc[0] / NN, cmy = cmacc[1] / NN, cmz = cmacc[2] / NN;

    if (tid < HH) {
        int h = tid;
        float nx = y_pred[(b * HH + h) * 4 + 0];
        float ny = y_pred[(b * HH + h) * 4 + 1];
        float nz = y_pred[(b * HH + h) * 4 + 2];
        float d  = y_pred[(b * HH + h) * 4 + 3];
        float inv = 1.0f / sqrtf(nx * nx + ny * ny + nz * nz);
        nx *= inv; ny *= inv; nz *= inv;
        nx_s[h] = nx; ny_s[h] = ny; nz_s[h] = nz; d_s[h] = d;
        const float* w = ws + (size_t)(b * HH + h) * 4;
        // fixed-order sum of the 4 block partials, both chamfer terms equal
        sde_s[h] = ((w[0] + w[1]) + (w[2] + w[3])) * (2.0f / NN);
    }
    __syncthreads();

    if (tid < HH) {
        int h = tid;
        float mn = sde_s[0], mx = sde_s[0];
        for (int g = 1; g < HH; ++g) {
            mn = fminf(mn, sde_s[g]);
            mx = fmaxf(mx, sde_s[g]);
        }
        float sde  = sde_s[h];
        float conf = 1.0f - (sde - mn) / fabsf(mx - mn);
        conf_s[h]  = conf;
        bool valid = (sde <= 10.0f);
        bool sup   = false;
        if (valid) {
            for (int g = 0; g < HH; ++g) {
                if (g == h) continue;
                float c = nx_s[h] * nx_s[g] + ny_s[h] * ny_s[g] + nz_s[h] * nz_s[g];
                c = fminf(1.0f, fmaxf(-1.0f, c));
                float ang = acosf(c) * 57.29577951308232f;
                bool close = (ang < 30.0f) || (180.0f - ang < 30.0f);
                if (close && (sde_s[g] <= 10.0f) && (sde >= sde_s[g])) sup = true;
            }
        }
        keep_s[h] = (valid && !sup) ? 1 : 0;
    }
    __syncthreads();

    if (tid < HH) {
        int h = tid;
        // stable descending rank on key = keep ? conf : -inf (jnp.argsort(-key))
        float keyh = keep_s[h] ? conf_s[h] : -INFINITY;
        int pos = 0;
        for (int g = 0; g < HH; ++g) {
            float keyg = keep_s[g] ? conf_s[g] : -INFINITY;
            if (keyg > keyh || (keyg == keyh && g < h)) ++pos;
        }
        float nx = nx_s[h], ny = ny_s[h], nz = nz_s[h];
        float t  = nx * cmx + ny * cmy + nz * cmz + d_s[h];
        float px = cmx - t * nx, py = cmy - t * ny, pz = cmz - t * nz;

        float* o = out + (size_t)(b * HH + pos) * 8;
        if (keep_s[h]) {
            o[0] = nx; o[1] = ny; o[2] = nz;
            o[3] = px; o[4] = py; o[5] = pz;
            o[6] = conf_s[h];
            o[7] = sde_s[h];
        } else {
            for (int c = 0; c < 8; ++c) o[c] = 0.0f;
        }
    }
}

extern "C" void kernel_launch(void* const* d_in, const int* in_sizes, int n_in,
                              void* d_out, int out_size, void* d_ws, size_t ws_size,
                              hipStream_t stream) {
    const float* y_pred = (const float*)d_in[0];   // (8,16,4) f32
    const float* sp     = (const float*)d_in[1];   // (8,1024,3) f32
    float* out          = (float*)d_out;           // (8,16,8) f32
    float* ws           = (float*)d_ws;            // 512 floats of block sums

    chamfer_kernel<<<dim3(BB * HH * 4), dim3(TB), 0, stream>>>(y_pred, sp, ws);
    finalize_kernel<<<dim3(BB), dim3(TB), 0, stream>>>(ws, y_pred, sp, out);
}